// Round 15
// baseline (149.193 us; speedup 1.0000x reference)
//
#include <hip/hip_runtime.h>
#include <hip/hip_bf16.h>

// Linformer MHA, MI355X gfx950. Round 15: attn QBLK=256 (2 q-groups/wave,
// K/V frags in regs reused across groups, staging+barriers per q halved);
// Q pre-scaled by 0.125*log2(e) in k_q epilogue (EPI=3). GEMMs = round 14.
// Pipeline (stream-ordered aliasing, ws = 32MB exactly):
//   k_convert_a: q,k,v -> Xqb[0:4M) Xkb[4M:8M) Xvb[8M:12M); Wq/Wk/Wv/Wo -> [12M:16M)
//   k_kv   : K/V projections -> KbT/VbT in d_out
//   k_q    : Q projection (masked, pre-scaled) -> Qb @ [4M:8M)
//   k_convert_b: WkP/WvP -> [8M:12M)
//   k_linproj: -> Kp[0:2M) VpT[2M:4M)
//   attn   : -> Xo[8M:12M)
//   k_outproj: -> fp32 d_out

typedef __attribute__((ext_vector_type(4))) float  f32x4;
typedef __attribute__((ext_vector_type(8))) short  short8;
typedef __attribute__((ext_vector_type(4))) short  short4_t;
typedef __attribute__((ext_vector_type(2))) unsigned int uint32x2;
typedef __attribute__((ext_vector_type(8))) __bf16 bf16x8;
typedef unsigned short ushort_t;

#define DEV __device__ __forceinline__

constexpr int B_ = 2, S_ = 2048, D_ = 1024, H_ = 16, SP_ = 1024;
constexpr size_t M1 = 1u << 20;
constexpr size_t XQ_OFF = 0,      XK_OFF = 4*M1,  XV_OFF = 8*M1,
                 WQ_OFF = 12*M1,  WK_OFF = 13*M1, WV_OFF = 14*M1, WO_OFF = 15*M1,
                 QB_OFF = 4*M1,   KP_OFF = 0,     VPT_OFF = 2*M1,
                 WKPB_OFF = 8*M1, WVPB_OFF = 10*M1, XO_OFF = 8*M1;
constexpr float CSC = 0.18033688011112042f;   // 0.125 * log2(e)

DEV ushort_t f2bf(float f) {              // RNE fp32 -> bf16 bits
  unsigned u = __builtin_bit_cast(unsigned, f);
  unsigned r = ((u >> 16) & 1u) + 0x7FFFu;
  return (ushort_t)((u + r) >> 16);
}
DEV bf16x8 ld8(const ushort_t* p) {
  return __builtin_bit_cast(bf16x8, *reinterpret_cast<const short8*>(p));
}
DEV f32x4 mfma16(bf16x8 a, bf16x8 b, f32x4 c) {
  return __builtin_amdgcn_mfma_f32_16x16x32_bf16(a, b, c, 0, 0, 0);
}
DEV void gload16(const ushort_t* g, ushort_t* l) {   // 16B global -> LDS direct
  __builtin_amdgcn_global_load_lds(
      (const __attribute__((address_space(1))) void*)g,
      (__attribute__((address_space(3))) void*)l, 16, 0, 0);
}
DEV void cvt2048(const float* src, ushort_t* dst, int tid) {
  const size_t off = (size_t)tid * 8;
  float4 f0 = *reinterpret_cast<const float4*>(src + off);
  float4 f1 = *reinterpret_cast<const float4*>(src + off + 4);
  ushort_t t[8] = { f2bf(f0.x), f2bf(f0.y), f2bf(f0.z), f2bf(f0.w),
                    f2bf(f1.x), f2bf(f1.y), f2bf(f1.z), f2bf(f1.w) };
  *reinterpret_cast<short8*>(dst + off) = *reinterpret_cast<short8*>(t);
}

// ---------------------------------------------------------------------------
// Conversion A: q,k,v (12M) + Wq,Wk,Wv,Wo (4M) -> bf16. 8192 blocks x 2048 el.
// ---------------------------------------------------------------------------
__global__ __launch_bounds__(256) void k_convert_a(
    const float* __restrict__ q, const float* __restrict__ k,
    const float* __restrict__ v, const float* __restrict__ Wq,
    const float* __restrict__ Wk, const float* __restrict__ Wv,
    const float* __restrict__ Wo, ushort_t* __restrict__ ws)
{
  int blk = blockIdx.x; const float* src; ushort_t* dst;
  if      (blk < 2048) { src = q;  dst = ws + XQ_OFF; }
  else if (blk < 4096) { src = k;  dst = ws + XK_OFF; blk -= 2048; }
  else if (blk < 6144) { src = v;  dst = ws + XV_OFF; blk -= 4096; }
  else if (blk < 6656) { src = Wq; dst = ws + WQ_OFF; blk -= 6144; }
  else if (blk < 7168) { src = Wk; dst = ws + WK_OFF; blk -= 6656; }
  else if (blk < 7680) { src = Wv; dst = ws + WV_OFF; blk -= 7168; }
  else                 { src = Wo; dst = ws + WO_OFF; blk -= 7680; }
  cvt2048(src + (size_t)blk * 2048, dst + (size_t)blk * 2048, threadIdx.x);
}

// Conversion B: WkP, WvP (4M elems) -> bf16. 2048 blocks.
__global__ __launch_bounds__(256) void k_convert_b(
    const float* __restrict__ WkP, const float* __restrict__ WvP,
    ushort_t* __restrict__ ws)
{
  int blk = blockIdx.x; const float* src; ushort_t* dst;
  if (blk < 1024) { src = WkP; dst = ws + WKPB_OFF; }
  else            { src = WvP; dst = ws + WVPB_OFF; blk -= 1024; }
  cvt2048(src + (size_t)blk * 2048, dst + (size_t)blk * 2048, threadIdx.x);
}

// ---------------------------------------------------------------------------
// 64x128xK bf16 MFMA GEMM, 256 thr (4 waves), BK=64, single-buffered LDS,
// 128B rows XOR-swizzled (pre-swizzled global src, swizzled ds_read).
// EPI: 0 none, 1 mask-row, 2 exact-GELU, 3 mask-row + scale-by-CSC.
// OUTMODE: 0 bf16 C[m][n]; 1 fp32 C[m][n]; 2 bf16 Ct[b][n][s]; 3 bf16 Ct[n][m].
// ---------------------------------------------------------------------------
template<int BIAS, int EPI, int OUTMODE>
DEV void gemmT(const ushort_t* Ap, const ushort_t* Bp, const float* bias,
               const int* mask, void* Cp, int M, int N, int K)
{
  __shared__ __align__(16) ushort_t As[64 * 64];    // 8KB
  __shared__ __align__(16) ushort_t Bs[128 * 64];   // 16KB
  const int tid = threadIdx.x;

  const int gx = gridDim.x, gy = gridDim.y, nwg = gx * gy;
  int lin = blockIdx.y * gx + blockIdx.x;
  lin = (lin & 7) * (nwg >> 3) + (lin >> 3);
  const int m0 = (lin / gy) * 64, n0 = (lin % gy) * 128;

  const int w = tid >> 6, lane = tid & 63, lr = lane & 15, lg = lane >> 4;
  const int wm = (w >> 1) * 32, wn = (w & 1) * 64;
  const int rk7 = lr & 7;

  f32x4 acc[2][4];
#pragma unroll
  for (int i = 0; i < 2; ++i)
#pragma unroll
    for (int j = 0; j < 4; ++j) acc[i][j] = f32x4{0.f, 0.f, 0.f, 0.f};

  const int srow = tid >> 3;                          // 0..31
  const int schx = ((tid & 7) ^ (srow & 7)) * 8;      // pre-swizzled col off
  const ushort_t* Ag = Ap + (size_t)(m0 + srow) * K + schx;
  const ushort_t* Bg = Bp + (size_t)(n0 + srow) * K + schx;

  for (int k0 = 0; k0 < K; k0 += 64) {
    gload16(Ag + k0,                 As + tid*8);
    gload16(Ag + (size_t)32*K + k0,  As + 2048 + tid*8);
    gload16(Bg + k0,                 Bs + tid*8);
    gload16(Bg + (size_t)32*K + k0,  Bs + 2048 + tid*8);
    gload16(Bg + (size_t)64*K + k0,  Bs + 4096 + tid*8);
    gload16(Bg + (size_t)96*K + k0,  Bs + 6144 + tid*8);
    __syncthreads();

#pragma unroll
    for (int ks = 0; ks < 2; ++ks) {
      bf16x8 af[2], bfv[4];
#pragma unroll
      for (int i = 0; i < 2; ++i)
        af[i]  = ld8(&As[(wm + i*16 + lr)*64 + (((ks<<2)|lg) ^ rk7)*8]);
#pragma unroll
      for (int j = 0; j < 4; ++j)
        bfv[j] = ld8(&Bs[(wn + j*16 + lr)*64 + (((ks<<2)|lg) ^ rk7)*8]);
#pragma unroll
      for (int i = 0; i < 2; ++i)
#pragma unroll
        for (int j = 0; j < 4; ++j)
          acc[i][j] = mfma16(af[i], bfv[j], acc[i][j]);
    }
    __syncthreads();
  }

#pragma unroll
  for (int i = 0; i < 2; ++i) {
    const int mBase = m0 + wm + i*16 + 4*lg;
#pragma unroll
    for (int j = 0; j < 4; ++j) {
      const int n = n0 + wn + j*16 + lr;
      float vv[4];
#pragma unroll
      for (int r = 0; r < 4; ++r) {
        const int m = mBase + r;
        float v = acc[i][j][r];
        if (BIAS == 2) v += bias[n];
        if (BIAS == 1) v += bias[m];
        if (EPI == 1 || EPI == 3) v = mask[m] ? v : 0.f;
        if (EPI == 3)  v *= CSC;
        if (EPI == 2)  v = 0.5f * v * (1.f + erff(v * 0.70710678118654752f));
        vv[r] = v;
      }
      if (OUTMODE == 0) {
#pragma unroll
        for (int r = 0; r < 4; ++r)
          ((ushort_t*)Cp)[(size_t)(mBase + r) * N + n] = f2bf(vv[r]);
      } else if (OUTMODE == 1) {
#pragma unroll
        for (int r = 0; r < 4; ++r)
          ((float*)Cp)[(size_t)(mBase + r) * N + n] = vv[r];
      } else if (OUTMODE == 2) {       // Ct[b][n][s], s=m-b*S_ (K/V proj path)
        const int bb = mBase >> 11;
        const int sb = mBase & (S_ - 1);
        ushort_t t4[4] = { f2bf(vv[0]), f2bf(vv[1]), f2bf(vv[2]), f2bf(vv[3]) };
        *reinterpret_cast<short4_t*>(
            (ushort_t*)Cp + ((size_t)bb * D_ + n) * S_ + sb) =
            *reinterpret_cast<short4_t*>(t4);
      } else {                         // Ct[n][m], stride M (linproj V path)
        ushort_t t4[4] = { f2bf(vv[0]), f2bf(vv[1]), f2bf(vv[2]), f2bf(vv[3]) };
        *reinterpret_cast<short4_t*>(
            (ushort_t*)Cp + (size_t)n * M + mBase) =
            *reinterpret_cast<short4_t*>(t4);
      }
    }
  }
}

// --------------------------- kernel wrappers -------------------------------
__global__ __launch_bounds__(256) void k_kv(
    const float* __restrict__ bk, const float* __restrict__ bv,
    const int* __restrict__ mask, const ushort_t* __restrict__ ws,
    ushort_t* __restrict__ KbT, ushort_t* __restrict__ VbT)
{
  if (blockIdx.z == 0)
    gemmT<2, 1, 2>(ws + XK_OFF, ws + WK_OFF, bk, mask, KbT, B_*S_, D_, D_);
  else
    gemmT<2, 1, 2>(ws + XV_OFF, ws + WV_OFF, bv, mask, VbT, B_*S_, D_, D_);
}

__global__ __launch_bounds__(256) void k_q(
    const float* __restrict__ bq, const int* __restrict__ mask,
    const ushort_t* __restrict__ ws, ushort_t* __restrict__ Qb)
{
  gemmT<2, 3, 0>(ws + XQ_OFF, ws + WQ_OFF, bq, mask, Qb, B_*S_, D_, D_);
}

__global__ __launch_bounds__(256) void k_linproj(
    const float* __restrict__ bkP, const float* __restrict__ bvP,
    const ushort_t* __restrict__ ws, const ushort_t* __restrict__ KbT,
    const ushort_t* __restrict__ VbT, ushort_t* __restrict__ Kp,
    ushort_t* __restrict__ VpT)
{
  const int z = blockIdx.z, b = z >> 1, isv = z & 1;
  if (isv) {
    gemmT<1, 2, 3>(ws + WVPB_OFF, VbT + (size_t)b * D_ * S_, bvP,
                   nullptr, VpT + (size_t)b * D_ * SP_, SP_, D_, S_);
  } else {
    gemmT<1, 2, 0>(ws + WKPB_OFF, KbT + (size_t)b * D_ * S_, bkP,
                   nullptr, Kp + (size_t)b * SP_ * D_, SP_, D_, S_);
  }
}

__global__ __launch_bounds__(256) void k_outproj(
    const ushort_t* __restrict__ Xo, const ushort_t* __restrict__ Wob,
    const float* __restrict__ bo, float* __restrict__ out)
{
  gemmT<2, 0, 1>(Xo, Wob, bo, nullptr, out, B_*S_, D_, D_);
}

// ---------------------------------------------------------------------------
// Fused attention v7: 512 thr, QBLK=256 (each wave: 2 q-groups x 16 rows),
// KVBLK=64, LDS-staged K/V^T (gload, dbuf, XOR swizzle). K/V fragments loaded
// into registers ONCE per tile, reused by both q-groups. Swapped QK^T +
// cvt_pk P-pack (Q pre-scaled -> exp2 direct), per-lane scalar denominator.
// ---------------------------------------------------------------------------
__global__ __launch_bounds__(512, 2) void attn_kernel(
    const ushort_t* __restrict__ Qb, const ushort_t* __restrict__ Kp,
    const ushort_t* __restrict__ VpT, ushort_t* __restrict__ Xo)
{
  __shared__ __align__(16) ushort_t Ks[2][64 * 64];
  __shared__ __align__(16) ushort_t Vs[2][64 * 64];
  __shared__ __align__(16) ushort_t Pl[8][16][72];   // per-wave P [q][p+pad]

  const int b = blockIdx.z, h = blockIdx.y, s0 = blockIdx.x * 256;
  const int tid = threadIdx.x, w = tid >> 6, lane = tid & 63;
  const int lr = lane & 15, lg = lane >> 4;

  bf16x8 aq[2][2];
#pragma unroll
  for (int g = 0; g < 2; ++g) {
    const ushort_t* qp =
        Qb + (size_t)(b * S_ + s0 + g*128 + w*16 + lr) * D_ + h * 64;
    aq[g][0] = ld8(qp + 8*lg);
    aq[g][1] = ld8(qp + 32 + 8*lg);
  }

  const ushort_t* kbase = Kp  + (size_t)b * SP_ * D_ + h * 64;
  const ushort_t* vbase = VpT + (size_t)b * D_ * SP_ + (size_t)(h*64) * SP_;

  const int srow = tid >> 3, sch = tid & 7;
  const int schx = (sch ^ (srow & 7)) << 3;
  const int rk7 = lr & 7;

  f32x4 o[2][4];
#pragma unroll
  for (int g = 0; g < 2; ++g)
#pragma unroll
    for (int dt = 0; dt < 4; ++dt) o[g][dt] = f32x4{0.f, 0.f, 0.f, 0.f};
  float lsum4[2][4] = {};

  gload16(kbase + (size_t)srow * D_ + schx, Ks[0] + tid*8);
  gload16(vbase + (size_t)srow * SP_ + schx, Vs[0] + tid*8);
  __syncthreads();

  int cur = 0;
  for (int pt = 0; pt < SP_ / 64; ++pt) {
    if (pt + 1 < SP_ / 64) {
      const int p1 = (pt + 1) * 64;
      gload16(kbase + (size_t)(p1 + srow) * D_ + schx, Ks[cur^1] + tid*8);
      gload16(vbase + (size_t)srow * SP_ + p1 + schx, Vs[cur^1] + tid*8);
    }

    // ---- K and V fragments once per tile (shared by both q-groups) ----
    bf16x8 kf[4][2], vf[4][2];
#pragma unroll
    for (int nt = 0; nt < 4; ++nt) {
      const ushort_t* krow = Ks[cur] + (nt*16 + lr) * 64;
      kf[nt][0] = ld8(krow + ((lg       ^ rk7) << 3));
      kf[nt][1] = ld8(krow + (((4 + lg) ^ rk7) << 3));
      const ushort_t* vrow = Vs[cur] + (nt*16 + lr) * 64;
      vf[nt][0] = ld8(vrow + ((lg       ^ rk7) << 3));
      vf[nt][1] = ld8(vrow + (((4 + lg) ^ rk7) << 3));
    }

#pragma unroll
    for (int g = 0; g < 2; ++g) {
      // ---- S^T = K Q^T; P = exp2(S^T) (Q pre-scaled); pack + write ----
#pragma unroll
      for (int nt = 0; nt < 4; ++nt) {
        f32x4 a = f32x4{0.f, 0.f, 0.f, 0.f};
        a = mfma16(kf[nt][0], aq[g][0], a);
        a = mfma16(kf[nt][1], aq[g][1], a);
        const float e0 = __builtin_exp2f(a[0]);
        const float e1 = __builtin_exp2f(a[1]);
        const float e2 = __builtin_exp2f(a[2]);
        const float e3 = __builtin_exp2f(a[3]);
        lsum4[g][nt] += (e0 + e1) + (e2 + e3);
        unsigned p01, p23;
        asm("v_cvt_pk_bf16_f32 %0, %1, %2" : "=v"(p01) : "v"(e0), "v"(e1));
        asm("v_cvt_pk_bf16_f32 %0, %1, %2" : "=v"(p23) : "v"(e2), "v"(e3));
        uint32x2 pw; pw[0] = p01; pw[1] = p23;
        *reinterpret_cast<uint32x2*>(&Pl[w][lr][nt*16 + 4*lg]) = pw;
      }
      // ---- O += P @ V ----
      const bf16x8 pa0 = ld8(&Pl[w][lr][8*lg]);
      const bf16x8 pa1 = ld8(&Pl[w][lr][32 + 8*lg]);
#pragma unroll
      for (int dt = 0; dt < 4; ++dt) {
        o[g][dt] = mfma16(pa0, vf[dt][0], o[g][dt]);
        o[g][dt] = mfma16(pa1, vf[dt][1], o[g][dt]);
      }
    }

    __syncthreads();
    cur ^= 1;
  }

  // ---- denominators + output per group ----
#pragma unroll
  for (int g = 0; g < 2; ++g) {
    float lsum = (lsum4[g][0] + lsum4[g][1]) + (lsum4[g][2] + lsum4[g][3]);
    lsum += __shfl_xor(lsum, 16, 64);
    lsum += __shfl_xor(lsum, 32, 64);        // every lane: denom for q=lr
    float linv[4];
#pragma unroll
    for (int r = 0; r < 4; ++r)
      linv[r] = 1.f / __shfl(lsum, 4*lg + r, 64);
#pragma unroll
    for (int dt = 0; dt < 4; ++dt)
#pragma unroll
      for (int r = 0; r < 4; ++r) {
        const int srow2 = s0 + g*128 + w*16 + 4*lg + r;
        Xo[(size_t)(b * S_ + srow2) * D_ + h*64 + dt*16 + lr] =
            f2bf(o[g][dt][r] * linv[r]);
      }
  }
}

// ------------------------------- launch ------------------------------------
extern "C" void kernel_launch(void* const* d_in, const int* in_sizes, int n_in,
                              void* d_out, int out_size, void* d_ws, size_t ws_size,
                              hipStream_t stream)
{
  const float* q   = (const float*)d_in[0];
  const float* k   = (const float*)d_in[1];
  const float* v   = (const float*)d_in[2];
  const int*   msk = (const int*)d_in[3];
  const float* Wq  = (const float*)d_in[4];
  const float* bq  = (const float*)d_in[5];
  const float* Wk  = (const float*)d_in[6];
  const float* bk  = (const float*)d_in[7];
  const float* Wv  = (const float*)d_in[8];
  const float* bv  = (const float*)d_in[9];
  const float* Wo  = (const float*)d_in[10];
  const float* bo  = (const float*)d_in[11];
  const float* WkP = (const float*)d_in[12];
  const float* bkP = (const float*)d_in[13];
  const float* WvP = (const float*)d_in[14];
  const float* bvP = (const float*)d_in[15];

  ushort_t* ws  = (ushort_t*)d_ws;
  ushort_t* Qb  = ws + QB_OFF;
  ushort_t* Kp  = ws + KP_OFF;
  ushort_t* VpT = ws + VPT_OFF;
  ushort_t* Xo  = ws + XO_OFF;
  ushort_t* KbT = (ushort_t*)d_out;     // d_out as scratch until k_outproj
  ushort_t* VbT = KbT + 4 * M1;

  dim3 blk(256, 1, 1);
  k_convert_a<<<dim3(8192, 1, 1), blk, 0, stream>>>(q, k, v, Wq, Wk, Wv, Wo, ws);
  k_kv     <<<dim3(B_*S_/64, D_/128, 2), blk, 0, stream>>>(bk, bv, msk, ws, KbT, VbT);
  k_q      <<<dim3(B_*S_/64, D_/128, 1), blk, 0, stream>>>(bq, msk, ws, Qb);
  k_convert_b<<<dim3(2048, 1, 1), blk, 0, stream>>>(WkP, WvP, ws);
  k_linproj<<<dim3(SP_/64,  D_/128, 4), blk, 0, stream>>>(bkP, bvP, ws, KbT, VbT, Kp, VpT);
  attn_kernel<<<dim3(S_/256, H_, B_), dim3(512,1,1), 0, stream>>>(Qb, Kp, VpT, Xo);
  k_outproj<<<dim3(B_*S_/64, D_/128, 1), blk, 0, stream>>>(Xo, ws + WO_OFF, bo, (float*)d_out);
}